// Round 10
// baseline (17827.599 us; speedup 1.0000x reference)
//
#include <hip/hip_runtime.h>
#include <math.h>

#define L_SEQ 512
#define BATCH 16
#define D_IN  41
#define HD    800
#define G4    3200   // 4*H
#define A2H   1600   // 2*H
#define NA    20
#define NWG   50     // blocks per direction (16 hidden units each)

typedef float v2f __attribute__((ext_vector_type(2)));

// workspace layout (float offsets). Peak ~178 MiB.
#define OFF_A   ((size_t)0)                                   // pre dir-f: [50][8192][64]
#define OFF_B   (OFF_A + (size_t)L_SEQ * BATCH * G4)          // pre dir-b
#define OFF_H   (OFF_B + (size_t)L_SEQ * BATCH * G4)          // h1 / h2: [512][16][1600]
#define OFF_DIH (OFF_H + (size_t)L_SEQ * BATCH * A2H)         // [512][16][3]
#define OFF_BAR (OFF_DIH + (size_t)L_SEQ * BATCH * 3)         // flag lines
#define FLG_STRIDE 32                                          // 128B per flag line
#define NREP 8                                                 // flag replicas per dir
#define DIR_STRIDE (NREP * NWG * FLG_STRIDE)                   // per-direction flag region
#define LAUNCH_STRIDE (2 * DIR_STRIDE)

static __device__ __forceinline__ float sigf(float x) {
    return 1.0f / (1.0f + __expf(-x));
}

// ---------------------------------------------------------------------------
// Flat replicated-flag barrier (per direction, NWG blocks). PROVEN protocol:
//  - arrival: __syncthreads() first (drains this block's sc1 h-stores via the
//    vmcnt(0) it emits before s_barrier); THEN lanes 0..7 store the monotone
//    step value to 8 REPLICA lines (line-exclusive writes).
//  - detection: wave 0 polls replica set (wg & 7), one line per lane
//    (50 lanes); waves 1..7 sleep at the closing s_barrier.
// ---------------------------------------------------------------------------
static __device__ __forceinline__ void fbar3(int* flg, int wg, int v) {
    __syncthreads();
    if (threadIdx.x < NREP)
        __hip_atomic_store(flg + ((int)threadIdx.x * NWG + wg) * FLG_STRIDE, v,
                           __ATOMIC_RELAXED, __HIP_MEMORY_SCOPE_AGENT);
    if (threadIdx.x < 64) {
        int* base = flg + ((wg & (NREP - 1)) * NWG) * FLG_STRIDE;
        for (;;) {
            int v1 = (threadIdx.x < NWG)
                         ? __hip_atomic_load(base + (int)threadIdx.x * FLG_STRIDE,
                                             __ATOMIC_RELAXED, __HIP_MEMORY_SCOPE_AGENT)
                         : v;
            if (__all(v1 >= v)) break;
        }
    }
    __syncthreads();
}

__global__ void init_bar_kernel(int* bar) {
    for (int i = blockIdx.x * 256 + threadIdx.x; i < 2 * LAUNCH_STRIDE;
         i += gridDim.x * 256)
        bar[i] = 0;
}

// ---------------------------------------------------------------------------
// K1: layer-0 pre-activations in BLOCK-CONTIGUOUS layout:
//   pre[dir][wg][m][rl],  m = t*16+b, rl = gate*16+j (j = unit 0..15),
//   orig gate-row g = gate*800 + wg*16 + j.
// ---------------------------------------------------------------------------
__global__ void pre0_kernel(const float* __restrict__ x,
                            const float* __restrict__ Wf, const float* __restrict__ bif,
                            const float* __restrict__ bhf,
                            const float* __restrict__ Wb, const float* __restrict__ bib,
                            const float* __restrict__ bhb,
                            float* __restrict__ outF, float* __restrict__ outB) {
    const int tid = threadIdx.x;
    const int wg = blockIdx.x * 4 + (tid >> 6);
    if (wg >= NWG) return;
    const int rl = tid & 63;              // gate*16 + j
    const int gate = rl >> 4, j = rl & 15;
    const int g = gate * 800 + wg * 16 + j;
    const int m = blockIdx.y;             // m = t*16 + b
    const int dir = blockIdx.z;
    const int b = m & 15, t = m >> 4;
    const float* W  = dir ? Wb  : Wf;
    const float* bi = dir ? bib : bif;
    const float* bh = dir ? bhb : bhf;
    float acc = bi[g] + bh[g];
    const float* xr = x + ((size_t)b * L_SEQ + t) * D_IN;   // x is [B][L][D]
    const float* wr = W + (size_t)g * D_IN;
    #pragma unroll
    for (int d = 0; d < D_IN; ++d) acc = fmaf(xr[d], wr[d], acc);
    (dir ? outB : outF)[((size_t)wg * (L_SEQ * BATCH) + m) * 64 + rl] = acc;
}

// ---------------------------------------------------------------------------
// K2: bidirectional LSTM recurrence. 100 blocks x 512 threads (cooperative):
// block = (dir = bid&1, wg = bid>>1 in 0..49); 16 hidden units per block.
// Round-10 change: phase A inner loop in PACKED fp32 (v_pk_fma_f32 via
// <2 x float> __builtin_elementwise_fma) -- 800 pk instrs/thread instead of
// 1600 scalar FMA: halves the VALU issue cost of phase A. Numerics are
// bit-identical (pk_fma is exact fma per lane-pair). Everything else
// (staging remap, b128 reads, swizzled scratch, fused pointwise, flag
// protocol) is byte-identical to round 9.
// ---------------------------------------------------------------------------
__launch_bounds__(512, 1)
__global__ void recur_kernel(const float* __restrict__ preF, const float* __restrict__ preB,
                             const float* __restrict__ WhhF, const float* __restrict__ WhhB,
                             float* __restrict__ hout, int* __restrict__ bar) {
    __shared__ float uni[35840];   // union: h stage (800*20=16000) / scratch (1024*35)
    const int tid = threadIdx.x;
    const int dir = blockIdx.x & 1;
    const int wg  = blockIdx.x >> 1;          // 0..49
    const int j0  = wg * 16;
    const float* pre = dir ? preB : preF;     // [50][8192][64] block-contiguous
    const float* Whh = dir ? WhhB : WhhF;     // [3200][800]
    int* flg = bar + dir * DIR_STRIDE;

    const int wv = tid >> 6;                  // wave 0..7
    const int lane = tid & 63;
    const int q = lane >> 2;                  // unit 0..15
    const int c = lane & 3;                   // k-sub 0..3
    const int k0 = wv * 100 + c * 25;         // contiguous k-slice start
    const int col2 = (4 * wv + c + 4 * q) & 31;   // swizzled scratch column

    // persistent W_hh slice: rows gi*800 + j0 + q, contiguous cols k0..k0+24
    float w[4][25];
    #pragma unroll
    for (int gi = 0; gi < 4; ++gi) {
        const float* wr = Whh + (size_t)(gi * HD + j0 + q) * HD + k0;
        #pragma unroll
        for (int kk = 0; kk < 25; ++kk) w[gi][kk] = wr[kk];
    }
    float cstate = 0.0f;                 // tid < 256: c-state for (jj=tid>>4, b=tid&15)
    const int jj2 = (tid >> 4) & 15, b2 = tid & 15;   // pointwise identity (tid<256)

    const float* pre_wg = pre + (size_t)wg * (L_SEQ * BATCH) * 64;

    // staging index precompute (bank-spread remap): 6 float4 + 1 float/thread
    int ofs[7], lds[7];
    {
        const int sb = (tid >> 2) & 15;       // staged batch row
        #pragma unroll
        for (int i = 0; i < 6; ++i) {
            int k = i * 128 + wv * 16 + (tid & 3) * 4;
            ofs[i] = 4 * (sb * A2H + k);
            lds[i] = k * 20 + sb;
        }
        // tail: k in [768, 800), one float per thread
        int bt = tid & 15, kt = 768 + (tid >> 4);
        ofs[6] = 4 * (bt * A2H + kt);
        lds[6] = kt * 20 + bt;
    }

    for (int it = 0; it < L_SEQ; ++it) {
        const int t = dir ? (L_SEQ - 1 - it) : it;

        if (it == 0) {
            for (int i = tid; i < 16000; i += 512) uni[i] = 0.0f;
        } else {
            const int tprev = dir ? (L_SEQ - it) : (it - 1);
            const float* hsrc = hout + ((size_t)tprev * BATCH) * A2H + dir * HD;
            float4 rr[6];
            float r1f;
            asm volatile(
                "global_load_dwordx4 %0, %7, %14 sc0 sc1\n\t"
                "global_load_dwordx4 %1, %8, %14 sc0 sc1\n\t"
                "global_load_dwordx4 %2, %9, %14 sc0 sc1\n\t"
                "global_load_dwordx4 %3, %10, %14 sc0 sc1\n\t"
                "global_load_dwordx4 %4, %11, %14 sc0 sc1\n\t"
                "global_load_dwordx4 %5, %12, %14 sc0 sc1\n\t"
                "global_load_dword %6, %13, %14 sc0 sc1\n\t"
                "s_waitcnt vmcnt(0)"
                : "=&v"(rr[0]), "=&v"(rr[1]), "=&v"(rr[2]), "=&v"(rr[3]),
                  "=&v"(rr[4]), "=&v"(rr[5]), "=&v"(r1f)
                : "v"(ofs[0]), "v"(ofs[1]), "v"(ofs[2]), "v"(ofs[3]),
                  "v"(ofs[4]), "v"(ofs[5]), "v"(ofs[6]), "s"(hsrc)
                : "memory");
            #pragma unroll
            for (int i = 0; i < 6; ++i) {
                uni[lds[i]]      = rr[i].x;
                uni[lds[i] + 20] = rr[i].y;
                uni[lds[i] + 40] = rr[i].z;
                uni[lds[i] + 60] = rr[i].w;
            }
            uni[lds[6]] = r1f;
        }

        // pv prefetch for the fused phase-B/pointwise threads (latency hides
        // under phase A)
        float pv[4];
        if (tid < 256) {
            #pragma unroll
            for (int gi = 0; gi < 4; ++gi)
                pv[gi] = pre_wg[((size_t)t * BATCH + b2) * 64 + gi * 16 + jj2];
        }
        __syncthreads();

        // phase A (packed): acc2[gi][p] (+)= w[gi][kk] * h[b=2p,2p+1][k0+kk]
        v2f acc2[4][8];
        #pragma unroll
        for (int gi = 0; gi < 4; ++gi)
            #pragma unroll
            for (int p = 0; p < 8; ++p) acc2[gi][p] = (v2f){0.0f, 0.0f};
        #pragma unroll
        for (int kk = 0; kk < 25; ++kk) {
            const float* hp = &uni[(k0 + kk) * 20];
            float4 h0 = *(const float4*)(hp);
            float4 h1 = *(const float4*)(hp + 4);
            float4 h2 = *(const float4*)(hp + 8);
            float4 h3 = *(const float4*)(hp + 12);
            v2f hv[8] = {(v2f){h0.x, h0.y}, (v2f){h0.z, h0.w},
                         (v2f){h1.x, h1.y}, (v2f){h1.z, h1.w},
                         (v2f){h2.x, h2.y}, (v2f){h2.z, h2.w},
                         (v2f){h3.x, h3.y}, (v2f){h3.z, h3.w}};
            #pragma unroll
            for (int gi = 0; gi < 4; ++gi) {
                const v2f wv2 = {w[gi][kk], w[gi][kk]};
                #pragma unroll
                for (int p = 0; p < 8; ++p)
                    acc2[gi][p] = __builtin_elementwise_fma(wv2, hv[p], acc2[gi][p]);
            }
        }
        __syncthreads();   // h consumed; reuse uni as reduce scratch

        // phase B write: single pass, swizzled column (sum is commutative)
        #pragma unroll
        for (int gi = 0; gi < 4; ++gi)
            #pragma unroll
            for (int p = 0; p < 8; ++p) {
                uni[((gi * 16 + q) * 16 + 2 * p)     * 35 + col2] = acc2[gi][p].x;
                uni[((gi * 16 + q) * 16 + 2 * p + 1) * 35 + col2] = acc2[gi][p].y;
            }
        __syncthreads();

        // fused phase B reduce + pointwise LSTM + h publish (tid < 256)
        if (tid < 256) {
            float s[4];
            #pragma unroll
            for (int gi = 0; gi < 4; ++gi) {
                const int base = ((gi * 16 + jj2) * 16 + b2) * 35;
                float acc3 = pv[gi];
                #pragma unroll
                for (int col = 0; col < 32; ++col) acc3 += uni[base + col];
                s[gi] = acc3;
            }
            float cn = sigf(s[1]) * cstate + sigf(s[0]) * tanhf(s[2]);
            cstate = cn;
            float hn = sigf(s[3]) * tanhf(cn);
            __hip_atomic_store(&hout[((size_t)t * BATCH + b2) * A2H + dir * HD + j0 + jj2],
                               hn, __ATOMIC_RELAXED, __HIP_MEMORY_SCOPE_AGENT);
        }
        if (it < L_SEQ - 1) fbar3(flg, wg, it + 1);
    }
}

// ---------------------------------------------------------------------------
// K3: pre1 GEMM in PERMUTED-N space (n' = wg*64 + rl), software-pipelined,
// PACKED fp32 micro-kernel (v_pk_fma_f32): acc2[8][4] v2f, 32 pk instrs per
// kk instead of 64 scalar FMA. 128x128 tile, BK=16. Epilogue coalesced in
// [wg][m][64].
// ---------------------------------------------------------------------------
static __device__ __forceinline__ int permn(int np) {
    return ((np & 63) >> 4) * 800 + (np >> 6) * 16 + (np & 15);
}

__launch_bounds__(256)
__global__ void gemm_pre1_kernel(const float* __restrict__ Ah,
                                 const float* __restrict__ WF, const float* __restrict__ biF,
                                 const float* __restrict__ bhF,
                                 const float* __restrict__ WB, const float* __restrict__ biB,
                                 const float* __restrict__ bhB,
                                 float* __restrict__ CF, float* __restrict__ CB) {
    __shared__ float As[16][132];
    __shared__ float Bs[16][132];
    const int dir = blockIdx.z;
    const float* Bw = dir ? WB : WF;
    const float* bi = dir ? biB : biF;
    const float* bh = dir ? bhB : bhF;
    float* C = dir ? CB : CF;
    const int n0 = blockIdx.x * 128;    // n' space
    const int m0 = blockIdx.y * 128;
    const int tid = threadIdx.x;
    const int mt = tid >> 4, nt = tid & 15;
    const int r = tid >> 2, kq = tid & 3;
    const float* arow0 = Ah + (size_t)(m0 + r) * A2H + kq * 4;
    const float* arow1 = Ah + (size_t)(m0 + r + 64) * A2H + kq * 4;
    const float* brow0 = Bw + (size_t)permn(n0 + r) * A2H + kq * 4;
    const float* brow1 = Bw + (size_t)permn(n0 + r + 64) * A2H + kq * 4;

    v2f acc2[8][4];
    #pragma unroll
    for (int i = 0; i < 8; ++i)
        #pragma unroll
        for (int j = 0; j < 4; ++j) acc2[i][j] = (v2f){0.0f, 0.0f};

    // prologue: load tile k0=0
    float4 a0 = *(const float4*)(arow0);
    float4 a1 = *(const float4*)(arow1);
    float4 b0 = *(const float4*)(brow0);
    float4 b1 = *(const float4*)(brow1);

    for (int k0 = 0; k0 < A2H; k0 += 16) {
        __syncthreads();   // previous compute done; LDS reusable
        As[kq * 4 + 0][r] = a0.x;  As[kq * 4 + 1][r] = a0.y;
        As[kq * 4 + 2][r] = a0.z;  As[kq * 4 + 3][r] = a0.w;
        As[kq * 4 + 0][r + 64] = a1.x;  As[kq * 4 + 1][r + 64] = a1.y;
        As[kq * 4 + 2][r + 64] = a1.z;  As[kq * 4 + 3][r + 64] = a1.w;
        Bs[kq * 4 + 0][r] = b0.x;  Bs[kq * 4 + 1][r] = b0.y;
        Bs[kq * 4 + 2][r] = b0.z;  Bs[kq * 4 + 3][r] = b0.w;
        Bs[kq * 4 + 0][r + 64] = b1.x;  Bs[kq * 4 + 1][r + 64] = b1.y;
        Bs[kq * 4 + 2][r + 64] = b1.z;  Bs[kq * 4 + 3][r + 64] = b1.w;
        __syncthreads();
        if (k0 + 16 < A2H) {   // issue next tile; flies under compute
            a0 = *(const float4*)(arow0 + k0 + 16);
            a1 = *(const float4*)(arow1 + k0 + 16);
            b0 = *(const float4*)(brow0 + k0 + 16);
            b1 = *(const float4*)(brow1 + k0 + 16);
        }
        #pragma unroll
        for (int kk = 0; kk < 16; ++kk) {
            float av[8];
            v2f bv[4];
            #pragma unroll
            for (int j = 0; j < 8; ++j) av[j] = As[kk][mt * 8 + j];
            #pragma unroll
            for (int j = 0; j < 4; ++j)
                bv[j] = (v2f){Bs[kk][nt * 8 + 2 * j], Bs[kk][nt * 8 + 2 * j + 1]};
            #pragma unroll
            for (int i = 0; i < 8; ++i) {
                const v2f avv = {av[i], av[i]};
                #pragma unroll
                for (int j = 0; j < 4; ++j)
                    acc2[i][j] = __builtin_elementwise_fma(avv, bv[j], acc2[i][j]);
            }
        }
    }
    float bias[8];
    #pragma unroll
    for (int j = 0; j < 8; ++j) {
        int n = permn(n0 + nt * 8 + j);
        bias[j] = bi[n] + bh[n];
    }
    // coalesced epilogue: n'-run of 8 stays inside one [m][64] row segment
    const int npb = n0 + nt * 8;
    const int seg = npb >> 6;           // wg
    const int lo  = npb & 63;           // rl base (multiple of 8)
    #pragma unroll
    for (int i = 0; i < 8; ++i) {
        float* dst = C + ((size_t)seg * (L_SEQ * BATCH) + (m0 + mt * 8 + i)) * 64 + lo;
        #pragma unroll
        for (int j = 0; j < 4; ++j) {
            dst[2 * j]     = acc2[i][j].x + bias[2 * j];
            dst[2 * j + 1] = acc2[i][j].y + bias[2 * j + 1];
        }
    }
}

// ---------------------------------------------------------------------------
// K4: linear head + softmax over BATCH dim + dihedrals. One block per t.
// ---------------------------------------------------------------------------
__global__ void head_kernel(const float* __restrict__ out2,   // [8192][1600]
                            const float* __restrict__ Wlin,   // [20][1600]
                            const float* __restrict__ blin,   // [20]
                            const float* __restrict__ alphabet, // [20][3]
                            float* __restrict__ dih) {        // [512][16][3]
    __shared__ float lg[16][21];
    __shared__ float sal[20][3], cal[20][3];
    const int t = blockIdx.x;
    const int tid = threadIdx.x;
    if (tid < 60) {
        int a = tid / 3, d = tid - 3 * (tid / 3);
        float v = alphabet[a * 3 + d];
        sal[a][d] = sinf(v);
        cal[a][d] = cosf(v);
    }
    const int b = tid / 20, a = tid - 20 * (tid / 20);
    const float* orow = out2 + ((size_t)t * BATCH + b) * A2H;
    const float* wrow = Wlin + (size_t)a * A2H;
    float s = blin[a];
    for (int k = 0; k < A2H; k += 4) {
        float4 ov = *(const float4*)(orow + k);
        float4 wv = *(const float4*)(wrow + k);
        s = fmaf(ov.x, wv.x, s);
        s = fmaf(ov.y, wv.y, s);
        s = fmaf(ov.z, wv.z, s);
        s = fmaf(ov.w, wv.w, s);
    }
    lg[b][a] = s;
    __syncthreads();
    if (tid < NA) {   // softmax over b for column a = tid
        float mx = -1e30f;
        #pragma unroll
        for (int bb = 0; bb < BATCH; ++bb) mx = fmaxf(mx, lg[bb][tid]);
        float sum = 0.0f;
        #pragma unroll
        for (int bb = 0; bb < BATCH; ++bb) {
            float e = expf(lg[bb][tid] - mx);
            lg[bb][tid] = e;
            sum += e;
        }
        float inv = 1.0f / sum;
        #pragma unroll
        for (int bb = 0; bb < BATCH; ++bb) lg[bb][tid] *= inv;
    }
    __syncthreads();
    if (tid < 48) {
        int bb = tid / 3, dd = tid - 3 * (tid / 3);
        float ss = 0.0f, cc = 0.0f;
        #pragma unroll
        for (int aa = 0; aa < NA; ++aa) {
            float p = lg[bb][aa];
            ss = fmaf(p, sal[aa][dd], ss);
            cc = fmaf(p, cal[aa][dd], cc);
        }
        dih[((size_t)t * BATCH + bb) * 3 + dd] = atan2f(ss, cc);
    }
}

// ---------------------------------------------------------------------------
// K5: sequential NeRF chain. 1 block, lane b < 16 walks its batch serially.
// ---------------------------------------------------------------------------
__global__ void nerf_kernel(const float* __restrict__ dih, float* __restrict__ out) {
    const int b = threadIdx.x;
    if (b >= BATCH) return;
    const float BL0 = 145.801f, BL1 = 152.326f, BL2 = 132.868f;
    const float BA0 = 2.124f,   BA1 = 1.941f,   BA2 = 2.028f;
    const float rr[3] = {BL0, BL1, BL2};
    const float st3[3] = {sinf(BA0), sinf(BA1), sinf(BA2)};
    const float ct3[3] = {cosf(BA0), cosf(BA1), cosf(BA2)};
    float ax = 0.f, ay = 0.f, az = 0.f;
    float bx = BL0, by = 0.f, bz = 0.f;
    float ang = 3.14159265358979323846f - BA0;
    float cx = bx + BL1 * cosf(ang), cy = BL1 * sinf(ang), cz = 0.f;
    for (int l = 0; l < L_SEQ; ++l) {
        #pragma unroll
        for (int d = 0; d < 3; ++d) {
            const int s = l * 3 + d;
            const float r = rr[d], st = st3[d], ct = ct3[d];
            float ph = dih[((size_t)l * BATCH + b) * 3 + d];
            float sp, cp;
            __sincosf(ph, &sp, &cp);
            float d2x = -r * ct, d2y = r * st * cp, d2z = r * st * sp;
            float bcx = cx - bx, bcy = cy - by, bcz = cz - bz;
            float inv = 1.0f / (sqrtf(bcx * bcx + bcy * bcy + bcz * bcz) + 1e-8f);
            bcx *= inv; bcy *= inv; bcz *= inv;
            float abx = bx - ax, aby = by - ay, abz = bz - az;
            float nx = aby * bcz - abz * bcy;
            float ny = abz * bcx - abx * bcz;
            float nz = abx * bcy - aby * bcx;
            inv = 1.0f / (sqrtf(nx * nx + ny * ny + nz * nz) + 1e-8f);
            nx *= inv; ny *= inv; nz *= inv;
            float m1x = ny * bcz - nz * bcy;
            float m1y = nz * bcx - nx * bcz;
            float m1z = nx * bcy - ny * bcx;
            float dx = bcx * d2x + m1x * d2y + nx * d2z + cx;
            float dy = bcy * d2x + m1y * d2y + ny * d2z + cy;
            float dz = bcz * d2x + m1z * d2y + nz * d2z + cz;
            size_t o = ((size_t)s * BATCH + b) * 3;
            out[o + 0] = dx; out[o + 1] = dy; out[o + 2] = dz;
            ax = bx; ay = by; az = bz;
            bx = cx; by = cy; bz = cz;
            cx = dx; cy = dy; cz = dz;
        }
    }
}

// ---------------------------------------------------------------------------
extern "C" void kernel_launch(void* const* d_in, const int* in_sizes, int n_in,
                              void* d_out, int out_size, void* d_ws, size_t ws_size,
                              hipStream_t stream) {
    (void)in_sizes; (void)n_in; (void)out_size; (void)ws_size;
    const float* x        = (const float*)d_in[0];
    const float* W_ih_l0f = (const float*)d_in[1];
    const float* W_hh_l0f = (const float*)d_in[2];
    const float* b_ih_l0f = (const float*)d_in[3];
    const float* b_hh_l0f = (const float*)d_in[4];
    const float* W_ih_l0b = (const float*)d_in[5];
    const float* W_hh_l0b = (const float*)d_in[6];
    const float* b_ih_l0b = (const float*)d_in[7];
    const float* b_hh_l0b = (const float*)d_in[8];
    const float* W_ih_l1f = (const float*)d_in[9];
    const float* W_hh_l1f = (const float*)d_in[10];
    const float* b_ih_l1f = (const float*)d_in[11];
    const float* b_hh_l1f = (const float*)d_in[12];
    const float* W_ih_l1b = (const float*)d_in[13];
    const float* W_hh_l1b = (const float*)d_in[14];
    const float* b_ih_l1b = (const float*)d_in[15];
    const float* b_hh_l1b = (const float*)d_in[16];
    const float* W_lin    = (const float*)d_in[17];
    const float* b_lin    = (const float*)d_in[18];
    const float* alphabet = (const float*)d_in[19];

    float* ws  = (float*)d_ws;
    float* bufA = ws + OFF_A;
    float* bufB = ws + OFF_B;
    float* h12  = ws + OFF_H;    // h1, then reused as h2 (also the h ring)
    float* dih  = ws + OFF_DIH;
    int*   bar  = (int*)(ws + OFF_BAR);

    // 0. zero flag lines (ws is re-poisoned before every launch)
    hipLaunchKernelGGL(init_bar_kernel, dim3(32), dim3(256), 0, stream, bar);

    // 1. layer-0 pre-activations (both dirs), block-contiguous layout
    hipLaunchKernelGGL(pre0_kernel, dim3(13, L_SEQ * BATCH, 2), dim3(256), 0, stream,
                       x, W_ih_l0f, b_ih_l0f, b_hh_l0f,
                       W_ih_l0b, b_ih_l0b, b_hh_l0b, bufA, bufB);

    // 2. layer-0 recurrence -> h1 (cooperative, 100 blocks x 512)
    {
        const float* a0 = bufA; const float* a1 = bufB;
        const float* a2 = W_hh_l0f; const float* a3 = W_hh_l0b;
        float* a4 = h12; int* a5 = bar;
        void* args[] = {&a0, &a1, &a2, &a3, &a4, &a5};
        hipError_t e = hipLaunchCooperativeKernel((const void*)recur_kernel, dim3(100),
                                                  dim3(512), args, 0, stream);
        (void)e;
    }

    // 3. layer-1 pre-activations: big fp32 GEMM, overwrites bufA/bufB
    hipLaunchKernelGGL(gemm_pre1_kernel, dim3(G4 / 128, (L_SEQ * BATCH) / 128, 2),
                       dim3(256), 0, stream,
                       h12, W_ih_l1f, b_ih_l1f, b_hh_l1f,
                       W_ih_l1b, b_ih_l1b, b_hh_l1b, bufA, bufB);

    // 4. layer-1 recurrence -> h2 (aliases h1; fresh flag area)
    {
        const float* a0 = bufA; const float* a1 = bufB;
        const float* a2 = W_hh_l1f; const float* a3 = W_hh_l1b;
        float* a4 = h12; int* a5 = bar + LAUNCH_STRIDE;
        void* args[] = {&a0, &a1, &a2, &a3, &a4, &a5};
        hipError_t e = hipLaunchCooperativeKernel((const void*)recur_kernel, dim3(100),
                                                  dim3(512), args, 0, stream);
        (void)e;
    }

    // 5. head: linear + softmax(dim=batch) + dihedrals
    hipLaunchKernelGGL(head_kernel, dim3(L_SEQ), dim3(320), 0, stream,
                       h12, W_lin, b_lin, alphabet, dih);

    // 6. sequential NeRF extension
    hipLaunchKernelGGL(nerf_kernel, dim3(1), dim3(64), 0, stream,
                       dih, (float*)d_out);
}

// Round 11
// 13328.877 us; speedup vs baseline: 1.3375x; 1.3375x over previous
//
#include <hip/hip_runtime.h>
#include <math.h>

#define L_SEQ 512
#define BATCH 16
#define D_IN  41
#define HD    800
#define G4    3200   // 4*H
#define A2H   1600   // 2*H
#define NA    20
#define NWG   50     // blocks per direction (16 hidden units each)

// workspace layout (float offsets). Peak ~178 MiB.
#define OFF_A   ((size_t)0)                                   // pre dir-f: [50][8192][64]
#define OFF_B   (OFF_A + (size_t)L_SEQ * BATCH * G4)          // pre dir-b
#define OFF_H   (OFF_B + (size_t)L_SEQ * BATCH * G4)          // h1 / h2: [512][16][1600]
#define OFF_DIH (OFF_H + (size_t)L_SEQ * BATCH * A2H)         // [512][16][3]
#define OFF_BAR (OFF_DIH + (size_t)L_SEQ * BATCH * 3)         // flag lines
#define FLG_STRIDE 32                                          // 128B per flag line
#define NREP 8                                                 // flag replicas per dir
#define DIR_STRIDE (NREP * NWG * FLG_STRIDE)                   // per-direction flag region
#define LAUNCH_STRIDE (2 * DIR_STRIDE)

static __device__ __forceinline__ float sigf(float x) {
    return 1.0f / (1.0f + __expf(-x));
}

// ---------------------------------------------------------------------------
// Flat replicated-flag barrier (per direction, NWG blocks). PROVEN protocol:
//  - arrival: __syncthreads() first (drains this block's sc1 h-stores via the
//    vmcnt(0) it emits before s_barrier); THEN lanes 0..7 store the monotone
//    step value to 8 REPLICA lines (line-exclusive writes).
//  - detection: wave 0 polls replica set (wg & 7), one line per lane
//    (50 lanes); waves 1..7 sleep at the closing s_barrier.
// ---------------------------------------------------------------------------
static __device__ __forceinline__ void fbar3(int* flg, int wg, int v) {
    __syncthreads();
    if (threadIdx.x < NREP)
        __hip_atomic_store(flg + ((int)threadIdx.x * NWG + wg) * FLG_STRIDE, v,
                           __ATOMIC_RELAXED, __HIP_MEMORY_SCOPE_AGENT);
    if (threadIdx.x < 64) {
        int* base = flg + ((wg & (NREP - 1)) * NWG) * FLG_STRIDE;
        for (;;) {
            int v1 = (threadIdx.x < NWG)
                         ? __hip_atomic_load(base + (int)threadIdx.x * FLG_STRIDE,
                                             __ATOMIC_RELAXED, __HIP_MEMORY_SCOPE_AGENT)
                         : v;
            if (__all(v1 >= v)) break;
        }
    }
    __syncthreads();
}

__global__ void init_bar_kernel(int* bar) {
    for (int i = blockIdx.x * 256 + threadIdx.x; i < 2 * LAUNCH_STRIDE;
         i += gridDim.x * 256)
        bar[i] = 0;
}

// ---------------------------------------------------------------------------
// K1: layer-0 pre-activations in BLOCK-CONTIGUOUS layout:
//   pre[dir][wg][m][rl],  m = t*16+b, rl = gate*16+j (j = unit 0..15),
//   orig gate-row g = gate*800 + wg*16 + j.
// ---------------------------------------------------------------------------
__global__ void pre0_kernel(const float* __restrict__ x,
                            const float* __restrict__ Wf, const float* __restrict__ bif,
                            const float* __restrict__ bhf,
                            const float* __restrict__ Wb, const float* __restrict__ bib,
                            const float* __restrict__ bhb,
                            float* __restrict__ outF, float* __restrict__ outB) {
    const int tid = threadIdx.x;
    const int wg = blockIdx.x * 4 + (tid >> 6);
    if (wg >= NWG) return;
    const int rl = tid & 63;              // gate*16 + j
    const int gate = rl >> 4, j = rl & 15;
    const int g = gate * 800 + wg * 16 + j;
    const int m = blockIdx.y;             // m = t*16 + b
    const int dir = blockIdx.z;
    const int b = m & 15, t = m >> 4;
    const float* W  = dir ? Wb  : Wf;
    const float* bi = dir ? bib : bif;
    const float* bh = dir ? bhb : bhf;
    float acc = bi[g] + bh[g];
    const float* xr = x + ((size_t)b * L_SEQ + t) * D_IN;   // x is [B][L][D]
    const float* wr = W + (size_t)g * D_IN;
    #pragma unroll
    for (int d = 0; d < D_IN; ++d) acc = fmaf(xr[d], wr[d], acc);
    (dir ? outB : outF)[((size_t)wg * (L_SEQ * BATCH) + m) * 64 + rl] = acc;
}

// ---------------------------------------------------------------------------
// K2: bidirectional LSTM recurrence. 100 blocks x 512 threads (cooperative):
// block = (dir = bid&1, wg = bid>>1 in 0..49); 16 hidden units per block.
// Round-9 proven form (pk-FMA refuted in r10: VGPR pair-alignment spills):
//   - staging lane remap: lane l (wave wv), instr i stages h[b][k..k+3] with
//     b=(l>>2)&15, k=i*128+wv*16+(l&3)*4 -> LDS writes 2-way bank-aliased
//     (free), global reads 16 fully-used 64B segments/wave.
//   - phase A: thread (wv, q=lane>>2, c=lane&3) owns contiguous k-slice
//     [wv*100+c*25, +25), reads h via 4x ds_read_b128 (16-lane broadcast),
//     scalar FMA (w[4][25] overflows to AGPRs spill-free).
//   - phase B: single-pass swizzled scratch + fused pointwise.
// ---------------------------------------------------------------------------
__launch_bounds__(512, 1)
__global__ void recur_kernel(const float* __restrict__ preF, const float* __restrict__ preB,
                             const float* __restrict__ WhhF, const float* __restrict__ WhhB,
                             float* __restrict__ hout, int* __restrict__ bar) {
    __shared__ float uni[35840];   // union: h stage (800*20=16000) / scratch (1024*35)
    const int tid = threadIdx.x;
    const int dir = blockIdx.x & 1;
    const int wg  = blockIdx.x >> 1;          // 0..49
    const int j0  = wg * 16;
    const float* pre = dir ? preB : preF;     // [50][8192][64] block-contiguous
    const float* Whh = dir ? WhhB : WhhF;     // [3200][800]
    int* flg = bar + dir * DIR_STRIDE;

    const int wv = tid >> 6;                  // wave 0..7
    const int lane = tid & 63;
    const int q = lane >> 2;                  // unit 0..15
    const int c = lane & 3;                   // k-sub 0..3
    const int k0 = wv * 100 + c * 25;         // contiguous k-slice start
    const int col2 = (4 * wv + c + 4 * q) & 31;   // swizzled scratch column

    // persistent W_hh slice: rows gi*800 + j0 + q, contiguous cols k0..k0+24
    float w[4][25];
    #pragma unroll
    for (int gi = 0; gi < 4; ++gi) {
        const float* wr = Whh + (size_t)(gi * HD + j0 + q) * HD + k0;
        #pragma unroll
        for (int kk = 0; kk < 25; ++kk) w[gi][kk] = wr[kk];
    }
    float cstate = 0.0f;                 // tid < 256: c-state for (jj=tid>>4, b=tid&15)
    const int jj2 = (tid >> 4) & 15, b2 = tid & 15;   // pointwise identity (tid<256)

    const float* pre_wg = pre + (size_t)wg * (L_SEQ * BATCH) * 64;

    // staging index precompute (bank-spread remap): 6 float4 + 1 float/thread
    int ofs[7], lds[7];
    {
        const int sb = (tid >> 2) & 15;       // staged batch row
        #pragma unroll
        for (int i = 0; i < 6; ++i) {
            int k = i * 128 + wv * 16 + (tid & 3) * 4;
            ofs[i] = 4 * (sb * A2H + k);
            lds[i] = k * 20 + sb;
        }
        // tail: k in [768, 800), one float per thread
        int bt = tid & 15, kt = 768 + (tid >> 4);
        ofs[6] = 4 * (bt * A2H + kt);
        lds[6] = kt * 20 + bt;
    }

    for (int it = 0; it < L_SEQ; ++it) {
        const int t = dir ? (L_SEQ - 1 - it) : it;

        if (it == 0) {
            for (int i = tid; i < 16000; i += 512) uni[i] = 0.0f;
        } else {
            const int tprev = dir ? (L_SEQ - it) : (it - 1);
            const float* hsrc = hout + ((size_t)tprev * BATCH) * A2H + dir * HD;
            float4 rr[6];
            float r1f;
            asm volatile(
                "global_load_dwordx4 %0, %7, %14 sc0 sc1\n\t"
                "global_load_dwordx4 %1, %8, %14 sc0 sc1\n\t"
                "global_load_dwordx4 %2, %9, %14 sc0 sc1\n\t"
                "global_load_dwordx4 %3, %10, %14 sc0 sc1\n\t"
                "global_load_dwordx4 %4, %11, %14 sc0 sc1\n\t"
                "global_load_dwordx4 %5, %12, %14 sc0 sc1\n\t"
                "global_load_dword %6, %13, %14 sc0 sc1\n\t"
                "s_waitcnt vmcnt(0)"
                : "=&v"(rr[0]), "=&v"(rr[1]), "=&v"(rr[2]), "=&v"(rr[3]),
                  "=&v"(rr[4]), "=&v"(rr[5]), "=&v"(r1f)
                : "v"(ofs[0]), "v"(ofs[1]), "v"(ofs[2]), "v"(ofs[3]),
                  "v"(ofs[4]), "v"(ofs[5]), "v"(ofs[6]), "s"(hsrc)
                : "memory");
            #pragma unroll
            for (int i = 0; i < 6; ++i) {
                uni[lds[i]]      = rr[i].x;
                uni[lds[i] + 20] = rr[i].y;
                uni[lds[i] + 40] = rr[i].z;
                uni[lds[i] + 60] = rr[i].w;
            }
            uni[lds[6]] = r1f;
        }

        // pv prefetch for the fused phase-B/pointwise threads (latency hides
        // under phase A)
        float pv[4];
        if (tid < 256) {
            #pragma unroll
            for (int gi = 0; gi < 4; ++gi)
                pv[gi] = pre_wg[((size_t)t * BATCH + b2) * 64 + gi * 16 + jj2];
        }
        __syncthreads();

        // phase A: acc[gi][b] += w[gi][kk] * h[b][k0+kk]; b128 h reads
        float acc[4][16];
        #pragma unroll
        for (int gi = 0; gi < 4; ++gi)
            #pragma unroll
            for (int b = 0; b < 16; ++b) acc[gi][b] = 0.0f;
        #pragma unroll
        for (int kk = 0; kk < 25; ++kk) {
            const float* hp = &uni[(k0 + kk) * 20];
            float4 h0 = *(const float4*)(hp);
            float4 h1 = *(const float4*)(hp + 4);
            float4 h2 = *(const float4*)(hp + 8);
            float4 h3 = *(const float4*)(hp + 12);
            float hreg[16] = {h0.x, h0.y, h0.z, h0.w, h1.x, h1.y, h1.z, h1.w,
                              h2.x, h2.y, h2.z, h2.w, h3.x, h3.y, h3.z, h3.w};
            #pragma unroll
            for (int gi = 0; gi < 4; ++gi)
                #pragma unroll
                for (int b = 0; b < 16; ++b)
                    acc[gi][b] = fmaf(w[gi][kk], hreg[b], acc[gi][b]);
        }
        __syncthreads();   // h consumed; reuse uni as reduce scratch

        // phase B write: single pass, swizzled column (sum is commutative)
        #pragma unroll
        for (int gi = 0; gi < 4; ++gi)
            #pragma unroll
            for (int b = 0; b < 16; ++b)
                uni[((gi * 16 + q) * 16 + b) * 35 + col2] = acc[gi][b];
        __syncthreads();

        // fused phase B reduce + pointwise LSTM + h publish (tid < 256)
        if (tid < 256) {
            float s[4];
            #pragma unroll
            for (int gi = 0; gi < 4; ++gi) {
                const int base = ((gi * 16 + jj2) * 16 + b2) * 35;
                float acc2 = pv[gi];
                #pragma unroll
                for (int col = 0; col < 32; ++col) acc2 += uni[base + col];
                s[gi] = acc2;
            }
            float cn = sigf(s[1]) * cstate + sigf(s[0]) * tanhf(s[2]);
            cstate = cn;
            float hn = sigf(s[3]) * tanhf(cn);
            __hip_atomic_store(&hout[((size_t)t * BATCH + b2) * A2H + dir * HD + j0 + jj2],
                               hn, __ATOMIC_RELAXED, __HIP_MEMORY_SCOPE_AGENT);
        }
        if (it < L_SEQ - 1) fbar3(flg, wg, it + 1);
    }
}

// ---------------------------------------------------------------------------
// K3: pre1 GEMM in PERMUTED-N space (n' = wg*64 + rl), software-pipelined:
// per iter {write LDS, sync, issue NEXT tile's loads, compute} so global
// latency flies under the 1024-FMA compute block. 128x128 tile, 8x8 micro,
// BK=16. Epilogue coalesced in [wg][m][64].
// ---------------------------------------------------------------------------
static __device__ __forceinline__ int permn(int np) {
    return ((np & 63) >> 4) * 800 + (np >> 6) * 16 + (np & 15);
}

__launch_bounds__(256)
__global__ void gemm_pre1_kernel(const float* __restrict__ Ah,
                                 const float* __restrict__ WF, const float* __restrict__ biF,
                                 const float* __restrict__ bhF,
                                 const float* __restrict__ WB, const float* __restrict__ biB,
                                 const float* __restrict__ bhB,
                                 float* __restrict__ CF, float* __restrict__ CB) {
    __shared__ float As[16][132];
    __shared__ float Bs[16][132];
    const int dir = blockIdx.z;
    const float* Bw = dir ? WB : WF;
    const float* bi = dir ? biB : biF;
    const float* bh = dir ? bhB : bhF;
    float* C = dir ? CB : CF;
    const int n0 = blockIdx.x * 128;    // n' space
    const int m0 = blockIdx.y * 128;
    const int tid = threadIdx.x;
    const int mt = tid >> 4, nt = tid & 15;
    const int r = tid >> 2, kq = tid & 3;
    const float* arow0 = Ah + (size_t)(m0 + r) * A2H + kq * 4;
    const float* arow1 = Ah + (size_t)(m0 + r + 64) * A2H + kq * 4;
    const float* brow0 = Bw + (size_t)permn(n0 + r) * A2H + kq * 4;
    const float* brow1 = Bw + (size_t)permn(n0 + r + 64) * A2H + kq * 4;

    float acc[8][8];
    #pragma unroll
    for (int i = 0; i < 8; ++i)
        #pragma unroll
        for (int j = 0; j < 8; ++j) acc[i][j] = 0.0f;

    // prologue: load tile k0=0
    float4 a0 = *(const float4*)(arow0);
    float4 a1 = *(const float4*)(arow1);
    float4 b0 = *(const float4*)(brow0);
    float4 b1 = *(const float4*)(brow1);

    for (int k0 = 0; k0 < A2H; k0 += 16) {
        __syncthreads();   // previous compute done; LDS reusable
        As[kq * 4 + 0][r] = a0.x;  As[kq * 4 + 1][r] = a0.y;
        As[kq * 4 + 2][r] = a0.z;  As[kq * 4 + 3][r] = a0.w;
        As[kq * 4 + 0][r + 64] = a1.x;  As[kq * 4 + 1][r + 64] = a1.y;
        As[kq * 4 + 2][r + 64] = a1.z;  As[kq * 4 + 3][r + 64] = a1.w;
        Bs[kq * 4 + 0][r] = b0.x;  Bs[kq * 4 + 1][r] = b0.y;
        Bs[kq * 4 + 2][r] = b0.z;  Bs[kq * 4 + 3][r] = b0.w;
        Bs[kq * 4 + 0][r + 64] = b1.x;  Bs[kq * 4 + 1][r + 64] = b1.y;
        Bs[kq * 4 + 2][r + 64] = b1.z;  Bs[kq * 4 + 3][r + 64] = b1.w;
        __syncthreads();
        if (k0 + 16 < A2H) {   // issue next tile; flies under compute
            a0 = *(const float4*)(arow0 + k0 + 16);
            a1 = *(const float4*)(arow1 + k0 + 16);
            b0 = *(const float4*)(brow0 + k0 + 16);
            b1 = *(const float4*)(brow1 + k0 + 16);
        }
        #pragma unroll
        for (int kk = 0; kk < 16; ++kk) {
            float av[8], bv[8];
            #pragma unroll
            for (int j = 0; j < 8; ++j) av[j] = As[kk][mt * 8 + j];
            #pragma unroll
            for (int j = 0; j < 8; ++j) bv[j] = Bs[kk][nt * 8 + j];
            #pragma unroll
            for (int i = 0; i < 8; ++i)
                #pragma unroll
                for (int j = 0; j < 8; ++j)
                    acc[i][j] = fmaf(av[i], bv[j], acc[i][j]);
        }
    }
    float bias[8];
    #pragma unroll
    for (int j = 0; j < 8; ++j) {
        int n = permn(n0 + nt * 8 + j);
        bias[j] = bi[n] + bh[n];
    }
    // coalesced epilogue: n'-run of 8 stays inside one [m][64] row segment
    const int npb = n0 + nt * 8;
    const int seg = npb >> 6;           // wg
    const int lo  = npb & 63;           // rl base (multiple of 8)
    #pragma unroll
    for (int i = 0; i < 8; ++i) {
        float* dst = C + ((size_t)seg * (L_SEQ * BATCH) + (m0 + mt * 8 + i)) * 64 + lo;
        #pragma unroll
        for (int j = 0; j < 8; ++j) dst[j] = acc[i][j] + bias[j];
    }
}

// ---------------------------------------------------------------------------
// K4: linear head + softmax over BATCH dim + dihedrals. One block per t.
// ---------------------------------------------------------------------------
__global__ void head_kernel(const float* __restrict__ out2,   // [8192][1600]
                            const float* __restrict__ Wlin,   // [20][1600]
                            const float* __restrict__ blin,   // [20]
                            const float* __restrict__ alphabet, // [20][3]
                            float* __restrict__ dih) {        // [512][16][3]
    __shared__ float lg[16][21];
    __shared__ float sal[20][3], cal[20][3];
    const int t = blockIdx.x;
    const int tid = threadIdx.x;
    if (tid < 60) {
        int a = tid / 3, d = tid - 3 * (tid / 3);
        float v = alphabet[a * 3 + d];
        sal[a][d] = sinf(v);
        cal[a][d] = cosf(v);
    }
    const int b = tid / 20, a = tid - 20 * (tid / 20);
    const float* orow = out2 + ((size_t)t * BATCH + b) * A2H;
    const float* wrow = Wlin + (size_t)a * A2H;
    float s = blin[a];
    for (int k = 0; k < A2H; k += 4) {
        float4 ov = *(const float4*)(orow + k);
        float4 wv = *(const float4*)(wrow + k);
        s = fmaf(ov.x, wv.x, s);
        s = fmaf(ov.y, wv.y, s);
        s = fmaf(ov.z, wv.z, s);
        s = fmaf(ov.w, wv.w, s);
    }
    lg[b][a] = s;
    __syncthreads();
    if (tid < NA) {   // softmax over b for column a = tid
        float mx = -1e30f;
        #pragma unroll
        for (int bb = 0; bb < BATCH; ++bb) mx = fmaxf(mx, lg[bb][tid]);
        float sum = 0.0f;
        #pragma unroll
        for (int bb = 0; bb < BATCH; ++bb) {
            float e = expf(lg[bb][tid] - mx);
            lg[bb][tid] = e;
            sum += e;
        }
        float inv = 1.0f / sum;
        #pragma unroll
        for (int bb = 0; bb < BATCH; ++bb) lg[bb][tid] *= inv;
    }
    __syncthreads();
    if (tid < 48) {
        int bb = tid / 3, dd = tid - 3 * (tid / 3);
        float ss = 0.0f, cc = 0.0f;
        #pragma unroll
        for (int aa = 0; aa < NA; ++aa) {
            float p = lg[bb][aa];
            ss = fmaf(p, sal[aa][dd], ss);
            cc = fmaf(p, cal[aa][dd], cc);
        }
        dih[((size_t)t * BATCH + bb) * 3 + dd] = atan2f(ss, cc);
    }
}

// ---------------------------------------------------------------------------
// K5: sequential NeRF chain. 1 block, lane b < 16 walks its batch serially.
// ---------------------------------------------------------------------------
__global__ void nerf_kernel(const float* __restrict__ dih, float* __restrict__ out) {
    const int b = threadIdx.x;
    if (b >= BATCH) return;
    const float BL0 = 145.801f, BL1 = 152.326f, BL2 = 132.868f;
    const float BA0 = 2.124f,   BA1 = 1.941f,   BA2 = 2.028f;
    const float rr[3] = {BL0, BL1, BL2};
    const float st3[3] = {sinf(BA0), sinf(BA1), sinf(BA2)};
    const float ct3[3] = {cosf(BA0), cosf(BA1), cosf(BA2)};
    float ax = 0.f, ay = 0.f, az = 0.f;
    float bx = BL0, by = 0.f, bz = 0.f;
    float ang = 3.14159265358979323846f - BA0;
    float cx = bx + BL1 * cosf(ang), cy = BL1 * sinf(ang), cz = 0.f;
    for (int l = 0; l < L_SEQ; ++l) {
        #pragma unroll
        for (int d = 0; d < 3; ++d) {
            const int s = l * 3 + d;
            const float r = rr[d], st = st3[d], ct = ct3[d];
            float ph = dih[((size_t)l * BATCH + b) * 3 + d];
            float sp, cp;
            __sincosf(ph, &sp, &cp);
            float d2x = -r * ct, d2y = r * st * cp, d2z = r * st * sp;
            float bcx = cx - bx, bcy = cy - by, bcz = cz - bz;
            float inv = 1.0f / (sqrtf(bcx * bcx + bcy * bcy + bcz * bcz) + 1e-8f);
            bcx *= inv; bcy *= inv; bcz *= inv;
            float abx = bx - ax, aby = by - ay, abz = bz - az;
            float nx = aby * bcz - abz * bcy;
            float ny = abz * bcx - abx * bcz;
            float nz = abx * bcy - aby * bcx;
            inv = 1.0f / (sqrtf(nx * nx + ny * ny + nz * nz) + 1e-8f);
            nx *= inv; ny *= inv; nz *= inv;
            float m1x = ny * bcz - nz * bcy;
            float m1y = nz * bcx - nx * bcz;
            float m1z = nx * bcy - ny * bcx;
            float dx = bcx * d2x + m1x * d2y + nx * d2z + cx;
            float dy = bcy * d2x + m1y * d2y + ny * d2z + cy;
            float dz = bcz * d2x + m1z * d2y + nz * d2z + cz;
            size_t o = ((size_t)s * BATCH + b) * 3;
            out[o + 0] = dx; out[o + 1] = dy; out[o + 2] = dz;
            ax = bx; ay = by; az = bz;
            bx = cx; by = cy; bz = cz;
            cx = dx; cy = dy; cz = dz;
        }
    }
}

// ---------------------------------------------------------------------------
extern "C" void kernel_launch(void* const* d_in, const int* in_sizes, int n_in,
                              void* d_out, int out_size, void* d_ws, size_t ws_size,
                              hipStream_t stream) {
    (void)in_sizes; (void)n_in; (void)out_size; (void)ws_size;
    const float* x        = (const float*)d_in[0];
    const float* W_ih_l0f = (const float*)d_in[1];
    const float* W_hh_l0f = (const float*)d_in[2];
    const float* b_ih_l0f = (const float*)d_in[3];
    const float* b_hh_l0f = (const float*)d_in[4];
    const float* W_ih_l0b = (const float*)d_in[5];
    const float* W_hh_l0b = (const float*)d_in[6];
    const float* b_ih_l0b = (const float*)d_in[7];
    const float* b_hh_l0b = (const float*)d_in[8];
    const float* W_ih_l1f = (const float*)d_in[9];
    const float* W_hh_l1f = (const float*)d_in[10];
    const float* b_ih_l1f = (const float*)d_in[11];
    const float* b_hh_l1f = (const float*)d_in[12];
    const float* W_ih_l1b = (const float*)d_in[13];
    const float* W_hh_l1b = (const float*)d_in[14];
    const float* b_ih_l1b = (const float*)d_in[15];
    const float* b_hh_l1b = (const float*)d_in[16];
    const float* W_lin    = (const float*)d_in[17];
    const float* b_lin    = (const float*)d_in[18];
    const float* alphabet = (const float*)d_in[19];

    float* ws  = (float*)d_ws;
    float* bufA = ws + OFF_A;
    float* bufB = ws + OFF_B;
    float* h12  = ws + OFF_H;    // h1, then reused as h2 (also the h ring)
    float* dih  = ws + OFF_DIH;
    int*   bar  = (int*)(ws + OFF_BAR);

    // 0. zero flag lines (ws is re-poisoned before every launch)
    hipLaunchKernelGGL(init_bar_kernel, dim3(32), dim3(256), 0, stream, bar);

    // 1. layer-0 pre-activations (both dirs), block-contiguous layout
    hipLaunchKernelGGL(pre0_kernel, dim3(13, L_SEQ * BATCH, 2), dim3(256), 0, stream,
                       x, W_ih_l0f, b_ih_l0f, b_hh_l0f,
                       W_ih_l0b, b_ih_l0b, b_hh_l0b, bufA, bufB);

    // 2. layer-0 recurrence -> h1 (cooperative, 100 blocks x 512)
    {
        const float* a0 = bufA; const float* a1 = bufB;
        const float* a2 = W_hh_l0f; const float* a3 = W_hh_l0b;
        float* a4 = h12; int* a5 = bar;
        void* args[] = {&a0, &a1, &a2, &a3, &a4, &a5};
        hipError_t e = hipLaunchCooperativeKernel((const void*)recur_kernel, dim3(100),
                                                  dim3(512), args, 0, stream);
        (void)e;
    }

    // 3. layer-1 pre-activations: big fp32 GEMM, overwrites bufA/bufB
    hipLaunchKernelGGL(gemm_pre1_kernel, dim3(G4 / 128, (L_SEQ * BATCH) / 128, 2),
                       dim3(256), 0, stream,
                       h12, W_ih_l1f, b_ih_l1f, b_hh_l1f,
                       W_ih_l1b, b_ih_l1b, b_hh_l1b, bufA, bufB);

    // 4. layer-1 recurrence -> h2 (aliases h1; fresh flag area)
    {
        const float* a0 = bufA; const float* a1 = bufB;
        const float* a2 = W_hh_l1f; const float* a3 = W_hh_l1b;
        float* a4 = h12; int* a5 = bar + LAUNCH_STRIDE;
        void* args[] = {&a0, &a1, &a2, &a3, &a4, &a5};
        hipError_t e = hipLaunchCooperativeKernel((const void*)recur_kernel, dim3(100),
                                                  dim3(512), args, 0, stream);
        (void)e;
    }

    // 5. head: linear + softmax(dim=batch) + dihedrals
    hipLaunchKernelGGL(head_kernel, dim3(L_SEQ), dim3(320), 0, stream,
                       h12, W_lin, b_lin, alphabet, dih);

    // 6. sequential NeRF extension
    hipLaunchKernelGGL(nerf_kernel, dim3(1), dim3(64), 0, stream,
                       dih, (float*)d_out);
}